// Round 13
// baseline (67.050 us; speedup 1.0000x reference)
//
#include <hip/hip_runtime.h>
#include <math.h>

#define HIN 32
#define WIN 32
#define NITER 3

typedef float f2 __attribute__((ext_vector_type(2)));
static __device__ __forceinline__ f2 mk2(float a, float b) { f2 r; r.x = a; r.y = b; return r; }
static __device__ __forceinline__ f2 fma2(f2 a, f2 b, f2 c) { return __builtin_elementwise_fma(a, b, c); }

// ---- 8-lane sum entirely on the VALU pipe (DPP), no ds_swizzle ----
template <int CTRL>
__device__ __forceinline__ float dpp_add(float v) {
    int p = __builtin_amdgcn_update_dpp(0, __float_as_int(v), CTRL, 0xF, 0xF, true);
    return v + __int_as_float(p);
}
__device__ __forceinline__ float sum8(float v) {
    v = dpp_add<0xB1>(v);   // quad_perm xor1
    v = dpp_add<0x4E>(v);   // quad_perm xor2
    v = dpp_add<0x141>(v);  // row_half_mirror
    return v;
}

// ---- stage T taps of flipped weight into pk layout ----
//   wlds[vtap*640 + g*80 + ((m2+g)&3)*20 + l*2 + h]   (v_pk_fma_f32 pairs)
template <int TH, int TW>
__device__ __forceinline__ void stage_weights(const float* __restrict__ weight,
                                              float* __restrict__ wlds, int t) {
    constexpr int T = TH * TW;
    const int sg = (t >> 3) & 7;
    const int sm = t & 7;
    const int l0 = t >> 6;
    const int dbase = sg * 80 + (((sm >> 1) + sg) & 3) * 20 + (sm & 1);
#pragma unroll
    for (int k = 0; k < 2 * T; ++k) {
        const int vtap = k >> 1;
        const int chunk = k & 1;
        const int hh = (TH == 1) ? 1 : ((vtap / TW) * 2);
        const int ww = (TW == 1) ? 1 : ((vtap % TW) * 2);
        const int jflip = (2 - hh) * 3 + (2 - ww);  // compile-time flip
        const int l = chunk * 4 + l0;
        wlds[vtap * 640 + dbase + l * 2] = weight[(chunk * 256 + t) * 9 + jflip];
    }
}

// ---- stage input tile [yi][xi<XW][c], zero-filled OOB (makes priors
// branchless: OOB taps read zeros -> votes are exactly 0) ----
template <int NROWS, int NCHUNK, int XW>
__device__ __forceinline__ void stage_input(const float* __restrict__ in,
                                            float* __restrict__ ilds,
                                            int t, int n, int y0, int x0) {
    const int c = t >> 2, r = t & 3;
#pragma unroll
    for (int pp = r; pp < NROWS * NCHUNK; pp += 4) {
        const int yi = pp / NCHUNK, ch = pp % NCHUNK;  // compile-time folds
        const int y = y0 + yi;
        const int xc = x0 + ch * 4;
        float4 vv = {0.f, 0.f, 0.f, 0.f};
        if (y < HIN && xc < WIN)
            vv = *(const float4*)(in + (((size_t)(n * 64 + c) * HIN + y) * WIN + xc));
        ilds[(yi * XW + ch * 4 + 0) * 64 + c] = vv.x;
        ilds[(yi * XW + ch * 4 + 1) * 64 + c] = vv.y;
        ilds[(yi * XW + ch * 4 + 2) * 64 + c] = vv.z;
        ilds[(yi * XW + ch * 4 + 3) * 64 + c] = vv.w;
    }
}

// ---- priors for NP positions q0 + dq*pp, weight rows loaded ONCE and used
// for all NP (guaranteed sharing, not compiler CSE). Branchless: zero-filled
// tiles produce the required zero votes. ----
template <int TH, int TW, int NP, int XW>
__device__ __forceinline__ void compute_pri_multi(const float* __restrict__ ilds,
                                                  const float* __restrict__ wlds,
                                                  int q0, int dq, int x0, int g, int s,
                                                  f2 (&pri2)[NP][TH * TW][4]) {
#pragma unroll
    for (int i = 0; i < TH; ++i) {
#pragma unroll
        for (int j = 0; j < TW; ++j) {
            const int v = i * TW + j;
            float xv[NP][8];
#pragma unroll
            for (int pp = 0; pp < NP; ++pp) {
                const int w = (TW == 1) ? 1 : (j * 2);
                const int xi = ((q0 + dq * pp + w - 1) >> 1) - x0;
                const float4* xp = (const float4*)(ilds + (i * XW + xi) * 64 + s * 8);
                float4 a = xp[0], b = xp[1];
                xv[pp][0] = a.x; xv[pp][1] = a.y; xv[pp][2] = a.z; xv[pp][3] = a.w;
                xv[pp][4] = b.x; xv[pp][5] = b.y; xv[pp][6] = b.z; xv[pp][7] = b.w;
            }
            const float* wb = wlds + v * 640 + g * 80;
#pragma unroll
            for (int m2 = 0; m2 < 4; ++m2) {
                const float4* row = (const float4*)(wb + ((m2 + g) & 3) * 20);
                float4 w0 = row[0], w1 = row[1], w2 = row[2], w3 = row[3];
#pragma unroll
                for (int pp = 0; pp < NP; ++pp) {
                    f2 acc = mk2(0.f, 0.f);
                    acc = fma2(mk2(xv[pp][0], xv[pp][0]), mk2(w0.x, w0.y), acc);
                    acc = fma2(mk2(xv[pp][1], xv[pp][1]), mk2(w0.z, w0.w), acc);
                    acc = fma2(mk2(xv[pp][2], xv[pp][2]), mk2(w1.x, w1.y), acc);
                    acc = fma2(mk2(xv[pp][3], xv[pp][3]), mk2(w1.z, w1.w), acc);
                    acc = fma2(mk2(xv[pp][4], xv[pp][4]), mk2(w2.x, w2.y), acc);
                    acc = fma2(mk2(xv[pp][5], xv[pp][5]), mk2(w2.z, w2.w), acc);
                    acc = fma2(mk2(xv[pp][6], xv[pp][6]), mk2(w3.x, w3.y), acc);
                    acc = fma2(mk2(xv[pp][7], xv[pp][7]), mk2(w3.z, w3.w), acc);
                    pri2[pp][v][m2] = acc;
                }
            }
        }
    }
}

// ---- full routing for one position: unnormalized r[] carried across iters
// (normalize is scale-invariant); zero votes add Z = 72-8T to the deferred
// softmax denominator (shift-free: bounded logits). Returns val (+bias).
template <int T>
__device__ __forceinline__ float route_core(const f2 (&pri2)[T][4],
                                            const float* __restrict__ bias,
                                            int g, int s) {
    constexpr float Z = (float)(72 - 8 * T);
    f2 rr[4];
#pragma unroll
    for (int m2 = 0; m2 < 4; ++m2) {
        f2 a = mk2(0.f, 0.f);
#pragma unroll
        for (int v = 0; v < T; ++v) a += pri2[v][m2];
        rr[m2].x = sum8(a.x);
        rr[m2].y = sum8(a.y);
    }
    float r8v = 0.f;
#pragma unroll
    for (int it = 0; it < NITER; ++it) {
        f2 t2 = mk2(0.f, 0.f);
#pragma unroll
        for (int m2 = 0; m2 < 4; ++m2) t2 = fma2(rr[m2], rr[m2], t2);
        const float sn = t2.x + t2.y;
        const float inv = __builtin_amdgcn_rsqf(fmaxf(sn, 1e-24f));
        const f2 inv2 = mk2(inv, inv);
        f2 on2[4];
#pragma unroll
        for (int m2 = 0; m2 < 4; ++m2) on2[m2] = rr[m2] * inv2;

        float a8 = 0.f;
        f2 acc2[4];
#pragma unroll
        for (int m2 = 0; m2 < 4; ++m2) acc2[m2] = mk2(0.f, 0.f);
#pragma unroll
        for (int v = 0; v < T; ++v) {
            f2 d2 = mk2(0.f, 0.f);
#pragma unroll
            for (int m2 = 0; m2 < 4; ++m2) d2 = fma2(pri2[v][m2], on2[m2], d2);
            const float e = __expf(d2.x + d2.y);
            a8 += e;
            const f2 e2 = mk2(e, e);
#pragma unroll
            for (int m2 = 0; m2 < 4; ++m2) acc2[m2] = fma2(e2, pri2[v][m2], acc2[m2]);
        }
#pragma unroll
        for (int m2 = 0; m2 < 4; ++m2) {
            rr[m2].x = sum8(acc2[m2].x);
            rr[m2].y = sum8(acc2[m2].y);
        }
        if (it == NITER - 1) r8v = sum8(a8);  // denominator only needed once
    }
    const float invs = __builtin_amdgcn_rcpf(r8v + Z);  // zero votes: exp(0)=1
    const f2 invs2 = mk2(invs, invs);
    f2 o2[4];
#pragma unroll
    for (int m2 = 0; m2 < 4; ++m2) o2[m2] = rr[m2] * invs2;
    f2 s2 = mk2(0.f, 0.f);
#pragma unroll
    for (int m2 = 0; m2 < 4; ++m2) s2 = fma2(o2[m2], o2[m2], s2);
    const float sn = s2.x + s2.y;
    const float factor =
        sn * __builtin_amdgcn_rcpf(1.f + sn) * __builtin_amdgcn_rsqf(sn + 1e-12f);
    f2 osel = o2[0];
#pragma unroll
    for (int m2 = 1; m2 < 4; ++m2)
        if ((s >> 1) == m2) osel = o2[m2];
    float val = (s & 1) ? osel.y : osel.x;
    return val * factor + bias[g * 8 + s];
}

// ---- T=4: single position/wave (dual would spill: R5 lesson) ----
__device__ __forceinline__ void run_t4(
    const float* __restrict__ in, const float* __restrict__ weight,
    const float* __restrict__ bias, float* __restrict__ out,
    float* __restrict__ ilds, float* __restrict__ wlds, float* __restrict__ olds,
    int t, int n, int p, int pi, int qb, int x0) {
    stage_input<2, 2, 8>(in, ilds, t, n, pi, x0);
    stage_weights<2, 2>(weight, wlds, t);
    __syncthreads();
    const int wave = t >> 6, lane = t & 63, g = lane >> 3, s = lane & 7;
    f2 pa[1][4][4];
    compute_pri_multi<2, 2, 1, 8>(ilds, wlds, qb + 2 * wave, 0, x0, g, s, pa);
    olds[lane * 5 + wave] = route_core<4>(pa[0], bias, g, s);
    __syncthreads();
    const int c2 = t >> 2, w = t & 3;
    out[(((size_t)n * 64 + c2) * 64 + p) * 64 + qb + 2 * w] = olds[c2 * 5 + w];
}

// ---- T=2 dual-position: wave does q and q+8, weights loaded once ----
template <int TH, int TW, int XW>
__device__ __forceinline__ void run_dual(
    const float* __restrict__ in, const float* __restrict__ weight,
    const float* __restrict__ bias, float* __restrict__ out,
    float* __restrict__ ilds, float* __restrict__ wlds, float* __restrict__ olds,
    int t, int n, int p, int pi, int qb, int x0) {
    constexpr int T = TH * TW;
    stage_input<TH, XW / 4, XW>(in, ilds, t, n, pi, x0);
    stage_weights<TH, TW>(weight, wlds, t);
    __syncthreads();
    const int wave = t >> 6, lane = t & 63, g = lane >> 3, s = lane & 7;
    f2 pp2[2][T][4];
    compute_pri_multi<TH, TW, 2, XW>(ilds, wlds, qb + 2 * wave, 8, x0, g, s, pp2);
    olds[lane * 9 + wave] = route_core<T>(pp2[0], bias, g, s);
    olds[lane * 9 + wave + 4] = route_core<T>(pp2[1], bias, g, s);
    __syncthreads();
    const int c2 = t >> 2, w = t & 3;
    float* ob = out + (((size_t)n * 64 + c2) * 64 + p) * 64 + qb;
    ob[2 * w] = olds[c2 * 9 + w];
    ob[2 * w + 8] = olds[c2 * 9 + w + 4];
}

// ---- T=1 quad-position: wave does q, q+2, q+4, q+6; weights loaded once ----
__device__ __forceinline__ void run_quad1(
    const float* __restrict__ in, const float* __restrict__ weight,
    const float* __restrict__ bias, float* __restrict__ out,
    float* __restrict__ ilds, float* __restrict__ wlds, float* __restrict__ olds,
    int t, int n, int p, int pi, int q0, int x0) {
    stage_input<1, 4, 16>(in, ilds, t, n, pi, x0);
    stage_weights<1, 1>(weight, wlds, t);
    __syncthreads();
    const int wave = t >> 6, lane = t & 63, g = lane >> 3, s = lane & 7;
    f2 pq[4][1][4];
    compute_pri_multi<1, 1, 4, 16>(ilds, wlds, q0 + 8 * wave, 2, x0, g, s, pq);
#pragma unroll
    for (int k = 0; k < 4; ++k)
        olds[lane * 17 + wave * 4 + k] = route_core<1>(pq[k], bias, g, s);
    __syncthreads();
    const int c2 = t >> 2, w = t & 3;
    float* ob = out + (((size_t)n * 64 + c2) * 64 + p) * 64 + q0 + 8 * w;
#pragma unroll
    for (int k = 0; k < 4; ++k) ob[2 * k] = olds[c2 * 17 + 4 * w + k];
}

// Grid 1152, interleaved cycle of 9: {T4 x4, T2v x2, T2h x2, T1} per group so
// every CU gets a balanced mix (T4 blocks do ~3x the LDS work of T1).
__global__ __launch_bounds__(256) void caps_routing(
    const float* __restrict__ in, const float* __restrict__ weight,
    const float* __restrict__ bias, float* __restrict__ out) {
    __shared__ float ilds[16 * 64];   // input tile (max: 1x16 or 2x8 rows)
    __shared__ float wlds[4 * 640];   // staged taps (pk layout)
    __shared__ float olds[64 * 17];   // output staging (max: T1-quad)
    const int t = threadIdx.x;

    const int b = blockIdx.x;
    const int grp = b / 9;        // 0..127
    const int sel = b - grp * 9;  // 0..8

    if (sel < 4) {  // T4: p odd, q odd; 512 blocks x 4 positions
        const int idx = grp * 4 + sel;
        const int n = idx >> 8, r = idx & 255;
        const int pi = r >> 3, jq = r & 7;
        run_t4(in, weight, bias, out, ilds, wlds, olds,
               t, n, 2 * pi + 1, pi, 8 * jq + 1, 4 * jq);
    } else if (sel < 8) {  // dual paths: 256 blocks x 8 positions each
        const int idx = grp * 2 + (sel & 1);
        const int n = idx >> 7, r = idx & 127;
        const int pi = r >> 2, jq = r & 3;
        if (sel < 6)  // T2v: p odd, q even
            run_dual<2, 1, 8>(in, weight, bias, out, ilds, wlds, olds,
                              t, n, 2 * pi + 1, pi, 16 * jq, 8 * jq);
        else          // T2h: p even, q odd
            run_dual<1, 2, 12>(in, weight, bias, out, ilds, wlds, olds,
                               t, n, 2 * pi, pi, 16 * jq + 1, 8 * jq);
    } else {  // T1: p even, q even; 128 blocks x 16 positions (quad waves)
        const int n = grp >> 6, r = grp & 63;
        const int pi = r >> 1, jh = r & 1;
        run_quad1(in, weight, bias, out, ilds, wlds, olds,
                  t, n, 2 * pi, pi, 32 * jh, 16 * jh);
    }
}

extern "C" void kernel_launch(void* const* d_in, const int* in_sizes, int n_in,
                              void* d_out, int out_size, void* d_ws, size_t ws_size,
                              hipStream_t stream) {
    const float* in = (const float*)d_in[0];
    const float* weight = (const float*)d_in[1];
    const float* bias = (const float*)d_in[2];
    float* out = (float*)d_out;
    (void)d_ws; (void)ws_size;

    caps_routing<<<1152, 256, 0, stream>>>(in, weight, bias, out);
}